// Round 1
// baseline (476.350 us; speedup 1.0000x reference)
//
#include <hip/hip_runtime.h>
#include <hip/hip_bf16.h>
#include <math.h>

#define HD 256   // hidden dim (fixed per problem)

// ---------------- CSR build ----------------

__global__ void init_deg_kernel(int* __restrict__ deg, int* __restrict__ cursor, int n) {
    int i = blockIdx.x * blockDim.x + threadIdx.x;
    if (i < n) { deg[i] = 1; cursor[i] = 0; }   // 1 = self loop
}

__global__ void count_deg_kernel(const int* __restrict__ col, int E, int* __restrict__ deg) {
    int e = blockIdx.x * blockDim.x + threadIdx.x;
    if (e < E) atomicAdd(&deg[col[e]], 1);
}

// single-block exclusive scan over deg -> offs; also dinv[v] = rsqrt(deg[v])
__global__ __launch_bounds__(1024) void scan_kernel(const int* __restrict__ deg,
                                                    int* __restrict__ offs,
                                                    float* __restrict__ dinv, int n) {
    __shared__ int ps[1024];
    int tid = threadIdx.x;
    int chunk = (n + 1023) >> 10;
    int beg = tid * chunk;
    int end = min(beg + chunk, n);
    int s = 0;
    for (int i = beg; i < end; ++i) s += deg[i];
    ps[tid] = s;
    __syncthreads();
    for (int off = 1; off < 1024; off <<= 1) {
        int t = (tid >= off) ? ps[tid - off] : 0;
        __syncthreads();
        ps[tid] += t;
        __syncthreads();
    }
    int run = ps[tid] - s;  // exclusive prefix
    for (int i = beg; i < end; ++i) {
        offs[i] = run;
        run += deg[i];
        dinv[i] = rsqrtf((float)deg[i]);
    }
    if (tid == 1023) offs[n] = ps[1023];
}

__global__ void fill_csr_kernel(const int* __restrict__ ei, int E, int N,
                                const int* __restrict__ offs,
                                int* __restrict__ cursor, int* __restrict__ csr) {
    int idx = blockIdx.x * blockDim.x + threadIdx.x;
    int tot = E + N;
    if (idx >= tot) return;
    int r, c;
    if (idx < E) { r = ei[idx]; c = ei[E + idx]; }
    else         { r = c = idx - E; }                 // self loop
    int slot = atomicAdd(&cursor[c], 1);
    csr[offs[c] + slot] = r;
}

// ---------------- aggregation: out[v] = dinv[v] * sum_{u in in(v)} dinv[u]*h[u]  (+bias,relu) ----------------

template<bool BIAS_RELU>
__global__ __launch_bounds__(256) void agg_kernel(const float* __restrict__ h,
                                                  const int* __restrict__ csr,
                                                  const int* __restrict__ offs,
                                                  const float* __restrict__ dinv,
                                                  const float* __restrict__ bias,
                                                  float* __restrict__ out) {
    int v = blockIdx.x;
    int f = threadIdx.x;
    int beg = offs[v];
    int end = offs[v + 1];
    float acc = 0.f;
    for (int i = beg; i < end; ++i) {
        int u = csr[i];
        acc = fmaf(dinv[u], h[(size_t)u * HD + f], acc);
    }
    float r = acc * dinv[v];
    if (BIAS_RELU) {
        r += bias[f];
        r = fmaxf(r, 0.f);
    }
    out[(size_t)v * HD + f] = r;
}

// ---------------- f32 GEMM: C[M,256] = A[M,256] @ W[256,256] (+bias) ----------------
// BM=64, BN=128, BK=32, 256 threads, 4x8 register tile.

template<bool ADD_BIAS>
__global__ __launch_bounds__(256) void gemm256_kernel(const float* __restrict__ A,
                                                      const float* __restrict__ W,
                                                      const float* __restrict__ bias,
                                                      float* __restrict__ C, int M) {
    constexpr int BM = 64, BN = 128, BK = 32;
    __shared__ float As[BK][BM + 4];   // transposed A tile; +4 pad keeps 16B alignment & spreads banks
    __shared__ float Ws[BK][BN];

    const int tid  = threadIdx.x;
    const int row0 = blockIdx.x * BM;
    const int col0 = blockIdx.y * BN;
    const int ty = tid >> 4;   // 0..15 -> rows ty*4 .. ty*4+3
    const int tx = tid & 15;   // 0..15 -> cols tx*8 .. tx*8+7

    float acc[4][8];
#pragma unroll
    for (int i = 0; i < 4; ++i)
#pragma unroll
        for (int j = 0; j < 8; ++j) acc[i][j] = 0.f;

    for (int k0 = 0; k0 < HD; k0 += BK) {
        // stage A tile, transposed into As[k][m]
        for (int j = tid; j < (BM * BK) / 4; j += 256) {
            int r  = j >> 3;           // 0..63
            int kc = (j & 7) << 2;     // 0,4,...,28
            float4 v = make_float4(0.f, 0.f, 0.f, 0.f);
            int row = row0 + r;
            if (row < M)
                v = *reinterpret_cast<const float4*>(&A[(size_t)row * HD + k0 + kc]);
            As[kc + 0][r] = v.x;
            As[kc + 1][r] = v.y;
            As[kc + 2][r] = v.z;
            As[kc + 3][r] = v.w;
        }
        // stage W tile (linear)
        for (int j = tid; j < (BK * BN) / 4; j += 256) {
            int k = j >> 5;            // 0..31
            int c = (j & 31) << 2;     // 0,4,...,124
            *reinterpret_cast<float4*>(&Ws[k][c]) =
                *reinterpret_cast<const float4*>(&W[(size_t)(k0 + k) * HD + col0 + c]);
        }
        __syncthreads();

#pragma unroll 8
        for (int k = 0; k < BK; ++k) {
            float4 av  = *reinterpret_cast<const float4*>(&As[k][ty << 2]);
            float4 bv0 = *reinterpret_cast<const float4*>(&Ws[k][tx << 3]);
            float4 bv1 = *reinterpret_cast<const float4*>(&Ws[k][(tx << 3) + 4]);
            float a_[4] = {av.x, av.y, av.z, av.w};
            float b_[8] = {bv0.x, bv0.y, bv0.z, bv0.w, bv1.x, bv1.y, bv1.z, bv1.w};
#pragma unroll
            for (int i = 0; i < 4; ++i)
#pragma unroll
                for (int j = 0; j < 8; ++j)
                    acc[i][j] = fmaf(a_[i], b_[j], acc[i][j]);
        }
        __syncthreads();
    }

    float b8[8];
#pragma unroll
    for (int j = 0; j < 8; ++j)
        b8[j] = ADD_BIAS ? bias[col0 + (tx << 3) + j] : 0.f;

#pragma unroll
    for (int i = 0; i < 4; ++i) {
        int row = row0 + (ty << 2) + i;
        if (row >= M) continue;
        float4 o0, o1;
        o0.x = acc[i][0] + b8[0]; o0.y = acc[i][1] + b8[1];
        o0.z = acc[i][2] + b8[2]; o0.w = acc[i][3] + b8[3];
        o1.x = acc[i][4] + b8[4]; o1.y = acc[i][5] + b8[5];
        o1.z = acc[i][6] + b8[6]; o1.w = acc[i][7] + b8[7];
        *reinterpret_cast<float4*>(&C[(size_t)row * HD + col0 + (tx << 3)])     = o0;
        *reinterpret_cast<float4*>(&C[(size_t)row * HD + col0 + (tx << 3) + 4]) = o1;
    }
}

// ---------------- launch ----------------

static inline size_t align_up(size_t x, size_t a) { return (x + a - 1) & ~(a - 1); }

extern "C" void kernel_launch(void* const* d_in, const int* in_sizes, int n_in,
                              void* d_out, int out_size, void* d_ws, size_t ws_size,
                              hipStream_t stream) {
    const int N = in_sizes[0] / HD;
    const int E = in_sizes[1] / 2;

    const float* x   = (const float*)d_in[0];
    const int*   ei  = (const int*)d_in[1];
    const float* W1  = (const float*)d_in[2];
    const float* W11 = (const float*)d_in[3];
    const float* W2  = (const float*)d_in[4];
    const float* W3  = (const float*)d_in[5];
    const float* b1  = (const float*)d_in[6];
    const float* b11 = (const float*)d_in[7];
    const float* b2  = (const float*)d_in[8];
    const float* b3  = (const float*)d_in[9];

    float* out2 = (float*)d_out;
    float* out3 = out2 + (size_t)N * HD;

    // workspace carve
    char* p = (char*)d_ws;
    int*   deg    = (int*)p;   p += align_up((size_t)N * 4, 256);
    int*   offs   = (int*)p;   p += align_up((size_t)(N + 1) * 4, 256);
    int*   cursor = (int*)p;   p += align_up((size_t)N * 4, 256);
    float* dinv   = (float*)p; p += align_up((size_t)N * 4, 256);
    int*   csr    = (int*)p;   p += align_up((size_t)(E + N) * 4, 256);
    float* bufA   = (float*)p; p += align_up((size_t)N * HD * 4, 256);
    float* bufB   = (float*)p; p += align_up((size_t)N * HD * 4, 256);
    (void)ws_size; (void)n_in; (void)out_size;

    // --- build CSR of incoming edges (with self loops) ---
    init_deg_kernel<<<(N + 255) / 256, 256, 0, stream>>>(deg, cursor, N);
    count_deg_kernel<<<(E + 255) / 256, 256, 0, stream>>>(ei + E, E, deg);
    scan_kernel<<<1, 1024, 0, stream>>>(deg, offs, dinv, N);
    fill_csr_kernel<<<(E + N + 255) / 256, 256, 0, stream>>>(ei, E, N, offs, cursor, csr);

    dim3 gblk(256);
    dim3 ggrid((N + 63) / 64, 2);

    // layer 1: h1 = relu(Agg(x @ W1) + b1)
    gemm256_kernel<false><<<ggrid, gblk, 0, stream>>>(x, W1, nullptr, bufA, N);
    agg_kernel<true><<<N, 256, 0, stream>>>(bufA, csr, offs, dinv, b1, bufB);

    // layer 2: h2 = relu(Agg(h1 @ W1_1) + b1_1)
    gemm256_kernel<false><<<ggrid, gblk, 0, stream>>>(bufB, W11, nullptr, bufA, N);
    agg_kernel<true><<<N, 256, 0, stream>>>(bufA, csr, offs, dinv, b11, bufB);

    // shared aggregation: g = Agg(h2)   (Agg and GEMM commute)
    agg_kernel<false><<<N, 256, 0, stream>>>(bufB, csr, offs, dinv, nullptr, bufA);

    // heads: out2 = g @ W2 + b2 ; out3 = g @ W3 + b3
    gemm256_kernel<true><<<ggrid, gblk, 0, stream>>>(bufA, W2, b2, out2, N);
    gemm256_kernel<true><<<ggrid, gblk, 0, stream>>>(bufA, W3, b3, out3, N);
}